// Round 6
// baseline (346.628 us; speedup 1.0000x reference)
//
#include <hip/hip_runtime.h>
#include <hip/hip_bf16.h>

// GQA block for MI355X. bf16 MFMA 16x16x32 everywhere, fp32 accumulation.
// Round-6: round-2 verified flash math; 512-block grid (2 blocks/CU overlap);
// Ps stride 76 (conflict-free P writes); staging coverage AUDITED:
//   K tile 64x128 shorts = 1024 short8  -> 256 thr x 4 stores ✓
//   V tile 128x64 shorts = 1024 short8  -> 256 thr x 4 stores ✓

typedef __attribute__((ext_vector_type(8))) short short8;
typedef __attribute__((ext_vector_type(4))) short short4v;
typedef __attribute__((ext_vector_type(4))) float float4v;

#define C1F 0.12751743f   // (1/sqrt(128)) * log2(e)
#define B0F -16.0f        // fixed max offset in log2 units

#if defined(__has_builtin) && __has_builtin(__builtin_amdgcn_exp2f)
#define EXP2(x) __builtin_amdgcn_exp2f(x)
#else
#define EXP2(x) exp2f(x)
#endif

__device__ __forceinline__ short f2bf(float x) {
    __hip_bfloat16 h = __float2bfloat16(x);
    short s; __builtin_memcpy(&s, &h, sizeof(s)); return s;
}

__device__ __forceinline__ void gl16(const short* g, short* l) {
    __builtin_amdgcn_global_load_lds(
        (const __attribute__((address_space(1))) void*)g,
        (__attribute__((address_space(3))) void*)l, 16, 0, 0);
}

// ---------------- fp32 -> bf16 elementwise ----------------
__global__ __launch_bounds__(256) void cvt_bf16_kernel(const float* __restrict__ in,
                                                       short* __restrict__ out, int n) {
    int i = (blockIdx.x * 256 + threadIdx.x) * 4;
    if (i >= n) return;
    float4 v = *(const float4*)(in + i);
    short4v o;
    o[0] = f2bf(v.x); o[1] = f2bf(v.y); o[2] = f2bf(v.z); o[3] = f2bf(v.w);
    *(short4v*)(out + i) = o;
}

// ---------------- W[K,N] fp32 -> Wt[N,K] bf16 ----------------
__global__ __launch_bounds__(256) void transpose_cvt_kernel(const float* __restrict__ W,
                                                            short* __restrict__ Wt,
                                                            int K, int N) {
    __shared__ float tile[32][33];
    int n0 = blockIdx.x * 32, k0 = blockIdx.y * 32;
    int tx = threadIdx.x & 31, ty = threadIdx.x >> 5;
#pragma unroll
    for (int i = 0; i < 4; ++i) {
        int kk = ty + i * 8;
        tile[kk][tx] = W[(size_t)(k0 + kk) * N + n0 + tx];
    }
    __syncthreads();
#pragma unroll
    for (int i = 0; i < 4; ++i) {
        int nn = ty + i * 8;
        Wt[(size_t)(n0 + nn) * K + k0 + tx] = f2bf(tile[tx][nn]);
    }
}

// ---------------- GEMM (m97 pattern): C = A[M,K] @ Bt[N,K]^T + bias ----------------
// 128x128 tile, BK=32, 4 waves. global_load_lds width-16 staging.
// mode 0: fused QKV epilogue (Q->O0 [*,2048], K->O1 [*,512], V->O2 transposed [512,4096])
// mode 1: fp32 out Of [*,2048] + b0
__global__ __launch_bounds__(256) void gemm_dma_kernel(
    const short* __restrict__ A, const short* __restrict__ Bt,
    const float* __restrict__ b0, const float* __restrict__ b1, const float* __restrict__ b2,
    short* __restrict__ O0, short* __restrict__ O1, short* __restrict__ O2,
    float* __restrict__ Of, int K, int mode) {
    __shared__ short As[128 * 32];
    __shared__ short Bs[128 * 32];
    const int t = threadIdx.x, lane = t & 63, w = t >> 6;
    const int l15 = lane & 15, quad = lane >> 4;
    const int wm = (w & 1) * 64, wn = (w >> 1) * 64;
    const int m0 = blockIdx.y * 128, n0 = blockIdx.x * 128;
    const int r4 = lane >> 2, c8 = (lane & 3) * 8;
    const short* ga = A + (size_t)(m0 + w * 16 + r4) * K + c8;
    const short* gb = Bt + (size_t)(n0 + w * 16 + r4) * K + c8;
    short* lA = As + (w * 16) * 32;   // wave-uniform LDS base, dst = base + lane*16B
    short* lB = Bs + (w * 16) * 32;

    float4v acc[4][4] = {};

    for (int k0 = 0; k0 < K; k0 += 32) {
        gl16(ga + k0, lA);
        gl16(ga + (size_t)64 * K + k0, lA + 64 * 32);
        gl16(gb + k0, lB);
        gl16(gb + (size_t)64 * K + k0, lB + 64 * 32);
        __syncthreads();
        short8 af[4], bfr[4];
#pragma unroll
        for (int i = 0; i < 4; ++i)
            af[i] = *(const short8*)(As + (wm + i * 16 + l15) * 32 + quad * 8);
#pragma unroll
        for (int j = 0; j < 4; ++j)
            bfr[j] = *(const short8*)(Bs + (wn + j * 16 + l15) * 32 + quad * 8);
#pragma unroll
        for (int i = 0; i < 4; ++i)
#pragma unroll
            for (int j = 0; j < 4; ++j)
                acc[i][j] = __builtin_amdgcn_mfma_f32_16x16x32_bf16(af[i], bfr[j], acc[i][j], 0, 0, 0);
        __syncthreads();
    }

#pragma unroll
    for (int i = 0; i < 4; ++i) {
#pragma unroll
        for (int j = 0; j < 4; ++j) {
            const int col = n0 + wn + j * 16 + l15;
            const int row0 = m0 + wm + i * 16 + quad * 4;
            if (mode == 1) {
                const float bc = b0[col];
#pragma unroll
                for (int r = 0; r < 4; ++r)
                    Of[(size_t)(row0 + r) * 2048 + col] = acc[i][j][r] + bc;
            } else if (col < 2048) {
                const float bc = b0[col];
#pragma unroll
                for (int r = 0; r < 4; ++r)
                    O0[(size_t)(row0 + r) * 2048 + col] = f2bf(acc[i][j][r] + bc);
            } else if (col < 2560) {
                const int c = col - 2048;
                const float bc = b1[c];
#pragma unroll
                for (int r = 0; r < 4; ++r)
                    O1[(size_t)(row0 + r) * 512 + c] = f2bf(acc[i][j][r] + bc);
            } else {
                const int c = col - 2560;
                const float bc = b2[c];
#pragma unroll
                for (int r = 0; r < 4; ++r)
                    O2[(size_t)c * 4096 + row0 + r] = f2bf(acc[i][j][r] + bc);
            }
        }
    }
}

// ---------------- Flash attention, fixed-max exp2 softmax ----------------
// grid (S/32, G, B) = (64,4,2) = 512 blocks, 256 threads = 4 waves.
// Wave w: head = g + 4*w (jnp.tile: group = h % 4); all 4 waves share q-rows
// qt*32..+32 (each wave: mi=2 tiles of 16 for ITS head). K/V tile (64 keys)
// staged once serves the 4 heads. 55.5 KB LDS -> 2 blocks/CU co-resident.
#define PSTR 76   // Ps stride: P-write quads land at word-banks {0,24,16,8} -> no conflicts

__global__ __launch_bounds__(256, 2) void flash_kernel(
    const short* __restrict__ Qb, const short* __restrict__ Kb,
    const short* __restrict__ Vt, const int* __restrict__ mask,
    short* __restrict__ Ab) {
    __shared__ short Ks[64 * 136];      // [key][d], pad 136
    __shared__ short Vs[128 * 72];      // [d][key], pad 72
    __shared__ short Ps[4 * 32 * PSTR]; // per-wave P (32 q x 64 keys)
    __shared__ float mb[64];

    const int t = threadIdx.x;
    const int lane = t & 63, w = t >> 6;
    const int l15 = lane & 15, quad = lane >> 4;
    const int qt = blockIdx.x, g = blockIdx.y, b = blockIdx.z;
    const int h = g + 4 * w;
    const int q0 = qt * 32;

    // Q fragments: 2 m-frags x 4 k-steps
    short8 qf[2][4];
#pragma unroll
    for (int mi = 0; mi < 2; ++mi)
#pragma unroll
        for (int ks = 0; ks < 4; ++ks)
            qf[mi][ks] = *(const short8*)(Qb + (size_t)(b * 2048 + q0 + mi * 16 + l15) * 2048
                                          + h * 128 + ks * 32 + quad * 8);

    float4v o[2][8] = {};
    float rsum[2][4] = {};
    short* PsW = Ps + w * (32 * PSTR);

    // staging, 256 threads, 4 short8 stores each per tile:
    //   K: 64 rows x 128 shorts; kR in [0,16), rows kR+{0,16,32,48}; kC=(t&15)*8
    //   V: 128 rows x 64 shorts; vR in [0,32), rows vR+{0,32,64,96}; vC=(t&7)*8
    const int kR = t >> 4, kC = (t & 15) * 8;
    const int vR = t >> 3, vC = (t & 7) * 8;
    const short* kg = Kb + (size_t)(b * 2048 + kR) * 512 + g * 128 + kC;
    const short* vg = Vt + (size_t)(g * 128 + vR) * 4096 + (size_t)b * 2048 + vC;

    for (int kt = 0; kt < 32; ++kt) {
        const int kb = kt * 64;
        short8 kv0 = *(const short8*)(kg + (size_t)(kb +  0) * 512);
        short8 kv1 = *(const short8*)(kg + (size_t)(kb + 16) * 512);
        short8 kv2 = *(const short8*)(kg + (size_t)(kb + 32) * 512);
        short8 kv3 = *(const short8*)(kg + (size_t)(kb + 48) * 512);
        short8 vv0 = *(const short8*)(vg + (size_t)  0 * 4096 + kb);
        short8 vv1 = *(const short8*)(vg + (size_t) 32 * 4096 + kb);
        short8 vv2 = *(const short8*)(vg + (size_t) 64 * 4096 + kb);
        short8 vv3 = *(const short8*)(vg + (size_t) 96 * 4096 + kb);
        float mv = 0.f;
        if (t < 64) mv = mask[b * 2048 + kb + t] ? B0F : -1e30f;
        __syncthreads();   // all waves finished reads of previous tile
        *(short8*)(Ks + (kR +  0) * 136 + kC) = kv0;
        *(short8*)(Ks + (kR + 16) * 136 + kC) = kv1;
        *(short8*)(Ks + (kR + 32) * 136 + kC) = kv2;
        *(short8*)(Ks + (kR + 48) * 136 + kC) = kv3;
        *(short8*)(Vs + (vR +  0) * 72 + vC) = vv0;
        *(short8*)(Vs + (vR + 32) * 72 + vC) = vv1;
        *(short8*)(Vs + (vR + 64) * 72 + vC) = vv2;
        *(short8*)(Vs + (vR + 96) * 72 + vC) = vv3;
        if (t < 64) mb[t] = mv;
        __syncthreads();

        // S = Q @ K^T (raw dot; scale folded into exp2)
        float4v s[2][4] = {};
#pragma unroll
        for (int ks = 0; ks < 4; ++ks) {
            short8 bk[4];
#pragma unroll
            for (int j = 0; j < 4; ++j)
                bk[j] = *(const short8*)(Ks + (j * 16 + l15) * 136 + ks * 32 + quad * 8);
#pragma unroll
            for (int j = 0; j < 4; ++j) {
                s[0][j] = __builtin_amdgcn_mfma_f32_16x16x32_bf16(qf[0][ks], bk[j], s[0][j], 0, 0, 0);
                s[1][j] = __builtin_amdgcn_mfma_f32_16x16x32_bf16(qf[1][ks], bk[j], s[1][j], 0, 0, 0);
            }
        }
        // p = 2^(s*C1 + mb[key]) (mb = B0F or -1e30); row sums accumulate linearly
#pragma unroll
        for (int mi = 0; mi < 2; ++mi)
#pragma unroll
            for (int j = 0; j < 4; ++j) {
                const float mbias = mb[j * 16 + l15];
#pragma unroll
                for (int r = 0; r < 4; ++r) {
                    float p = EXP2(fmaf(s[mi][j][r], C1F, mbias));
                    rsum[mi][r] += p;
                    PsW[(mi * 16 + quad * 4 + r) * PSTR + j * 16 + l15] = f2bf(p);
                }
            }
        // O += P @ V (per-wave P slice; no barrier needed).
        // PSTR=76 breaks 16B alignment -> two 8B reads per A-frag (8B-aligned ✓).
#pragma unroll
        for (int ks2 = 0; ks2 < 2; ++ks2) {
            short8 pa[2];
#pragma unroll
            for (int mi = 0; mi < 2; ++mi) {
                const short* pp = PsW + (mi * 16 + l15) * PSTR + ks2 * 32 + quad * 8;
                short4v lo = *(const short4v*)(pp);
                short4v hi = *(const short4v*)(pp + 4);
                pa[mi][0] = lo[0]; pa[mi][1] = lo[1]; pa[mi][2] = lo[2]; pa[mi][3] = lo[3];
                pa[mi][4] = hi[0]; pa[mi][5] = hi[1]; pa[mi][6] = hi[2]; pa[mi][7] = hi[3];
            }
#pragma unroll
            for (int jj = 0; jj < 8; ++jj) {
                short8 bv = *(const short8*)(Vs + (jj * 16 + l15) * 72 + ks2 * 32 + quad * 8);
                o[0][jj] = __builtin_amdgcn_mfma_f32_16x16x32_bf16(pa[0], bv, o[0][jj], 0, 0, 0);
                o[1][jj] = __builtin_amdgcn_mfma_f32_16x16x32_bf16(pa[1], bv, o[1][jj], 0, 0, 0);
            }
        }
    }

    // normalize: reduce rsum across the 16 l15 lanes (keys dim), per (mi, r)
    float rinv[2][4];
#pragma unroll
    for (int mi = 0; mi < 2; ++mi)
#pragma unroll
        for (int r = 0; r < 4; ++r) {
            float v = rsum[mi][r];
            v += __shfl_xor(v, 1, 64); v += __shfl_xor(v, 2, 64);
            v += __shfl_xor(v, 4, 64); v += __shfl_xor(v, 8, 64);
            rinv[mi][r] = (v > 0.f) ? 1.f / v : 0.f;
        }
    const size_t ob = (size_t)(b * 2048 + q0) * 2048 + h * 128;
#pragma unroll
    for (int mi = 0; mi < 2; ++mi)
#pragma unroll
        for (int jj = 0; jj < 8; ++jj)
#pragma unroll
            for (int r = 0; r < 4; ++r)
                Ab[ob + (size_t)(mi * 16 + quad * 4 + r) * 2048 + jj * 16 + l15] =
                    f2bf(o[mi][jj][r] * rinv[mi][r]);
}

extern "C" void kernel_launch(void* const* d_in, const int* in_sizes, int n_in,
                              void* d_out, int out_size, void* d_ws, size_t ws_size,
                              hipStream_t stream) {
    (void)in_sizes; (void)n_in; (void)out_size; (void)ws_size;
    const float* X  = (const float*)d_in[0];
    const int* mask = (const int*)d_in[1];
    const float* Wq = (const float*)d_in[2];
    const float* bq = (const float*)d_in[3];
    const float* Wk = (const float*)d_in[4];
    const float* bk = (const float*)d_in[5];
    const float* Wv = (const float*)d_in[6];
    const float* bv = (const float*)d_in[7];
    const float* Wo = (const float*)d_in[8];
    const float* bo = (const float*)d_in[9];
    float* out = (float*)d_out;

    char* ws = (char*)d_ws;
    short* Xb     = (short*)(ws + 0);          // 16 MB (reused as Ab)
    short* WqkvT  = (short*)(ws + 16777216);   // 12 MB [3072,2048]
    short* Wot    = (short*)(ws + 29360128);   //  8 MB
    short* Qb     = (short*)(ws + 37748736);   // 16 MB
    short* Kb     = (short*)(ws + 54525952);   //  4 MB
    short* Vt     = (short*)(ws + 58720256);   //  4 MB
    short* Ab     = Xb;

    const int M = 4096, HID = 2048, KV = 512;

    cvt_bf16_kernel<<<8192, 256, 0, stream>>>(X, Xb, M * HID);
    transpose_cvt_kernel<<<dim3(64, 64), 256, 0, stream>>>(Wq, WqkvT, HID, HID);
    transpose_cvt_kernel<<<dim3(16, 64), 256, 0, stream>>>(Wk, WqkvT + (size_t)2048 * 2048, HID, KV);
    transpose_cvt_kernel<<<dim3(16, 64), 256, 0, stream>>>(Wv, WqkvT + (size_t)2560 * 2048, HID, KV);
    transpose_cvt_kernel<<<dim3(64, 64), 256, 0, stream>>>(Wo, Wot, HID, HID);

    // fused Q|K|V projection: N = 3072
    gemm_dma_kernel<<<dim3(24, 32), 256, 0, stream>>>(
        Xb, WqkvT, bq, bk, bv, Qb, Kb, Vt, nullptr, HID, 0);

    flash_kernel<<<dim3(64, 4, 2), 256, 0, stream>>>(Qb, Kb, Vt, mask, Ab);

    gemm_dma_kernel<<<dim3(16, 32), 256, 0, stream>>>(
        Ab, Wot, bo, nullptr, nullptr, nullptr, nullptr, nullptr, out, HID, 1);
}